// Round 7
// baseline (551.428 us; speedup 1.0000x reference)
//
#include <hip/hip_runtime.h>
#include <math.h>

#define NN 512
#define NBC 128   // B*2

typedef __attribute__((ext_vector_type(8))) __bf16 v8bf;
typedef __attribute__((ext_vector_type(4))) float v4f;

// round-to-nearest-even bf16 split: v = hi + lo (+O(2^-17) rel)
__device__ __forceinline__ void bsplit(float v, unsigned short& h, unsigned short& l) {
    unsigned u  = __builtin_bit_cast(unsigned, v);
    unsigned hb = (u + 0x7fffu + ((u >> 16) & 1u)) & 0xffff0000u;
    float hf    = __builtin_bit_cast(float, hb);
    h = (unsigned short)(hb >> 16);
    float lof   = v - hf;
    unsigned ul = __builtin_bit_cast(unsigned, lof);
    l = (unsigned short)((ul + 0x7fffu + ((ul >> 16) & 1u)) >> 16);
}

// async global->LDS, 16B per lane; LDS dest must be wave-uniform (HW adds lane*16)
__device__ __forceinline__ void gl_lds16(const unsigned short* g, unsigned short* l) {
    __builtin_amdgcn_global_load_lds(
        (const __attribute__((address_space(1))) void*)g,
        (__attribute__((address_space(3))) void*)l, 16, 0, 0);
}

// Fragment-tile layout for an [n][k] operand (n = MFMA 16-dim, k = K dim):
//   addr(shorts) = ((n/16)*(kext/32) + k/32)*512 + ((n%16) + 16*((k%32)/8))*8 + k%8
// A wave's fragment (n = base+m0, k = ko+quad*8) is ONE contiguous 1KB chunk.
__device__ __forceinline__ size_t fragaddr(int n, int k, int kext) {
    return ((size_t)(n >> 4) * (kext >> 5) + (k >> 5)) * 512
         + (size_t)(((n & 15) + 16 * ((k >> 3) & 3)) * 8 + (k & 7));
}
template<int KEXT>
__device__ __forceinline__ size_t fa(int n, int k) {
    return ((size_t)(n >> 4) * (KEXT >> 5) + (k >> 5)) * 512
         + (size_t)(((n & 15) + 16 * ((k >> 3) & 3)) * 8 + (k & 7));
}

// ---------------- degree (fallback path only) -------------------------------
__global__ __launch_bounds__(256) void k_rowsum(const float* __restrict__ adj,
                                                float* __restrict__ dinv) {
    int wave = blockIdx.x * 4 + (threadIdx.x >> 6);
    int lane = threadIdx.x & 63;
    const float4* row = (const float4*)(adj + (size_t)wave * NN);
    float4 v0 = row[lane], v1 = row[lane + 64];
    float s = v0.x + v0.y + v0.z + v0.w + v1.x + v1.y + v1.z + v1.w;
    #pragma unroll
    for (int off = 32; off; off >>= 1) s += __shfl_down(s, off, 64);
    if (lane == 0) dinv[wave] = rsqrtf(1.0f + s);
}

// ---------------- weight prep: dst = split(w[p][h]) in fragment order -------
struct WJob  { const float* w; unsigned short* dh; unsigned short* dl; int HI; int HO; int HOP; };
struct WJobs { WJob j[8]; };
__global__ __launch_bounds__(256) void k_wprep(WJobs jobs) {
    WJob jb = jobs.j[blockIdx.y];
    int idx = blockIdx.x * 256 + threadIdx.x;
    if (idx >= jb.HOP * jb.HI) return;
    int h = idx / jb.HI, p = idx % jb.HI;
    float v = (h < jb.HO) ? jb.w[p * jb.HO + h] : 0.f;
    unsigned short hh, ll; bsplit(v, hh, ll);
    size_t oa = fragaddr(h, p, jb.HI);
    jb.dh[oa] = hh; jb.dl[oa] = ll;
}

// ======================= FUSED PER-BC GCN CHAIN ============================
// One 1024-thread block per bc.  __syncthreads() = layer barrier.
// A panel (512 x 32, hi+lo = 64KB) single-buffered in LDS; Z panel <= 16KB.
// Layer 1 generates An on the fly (convert fused; writes frag-order copy to
// global for layers 2-4, which re-stage it via gl_lds — same-block write+read
// so L2/L3 serve it).  All MFMA orders identical to the verified R2 kernel.

// ---- An@Z layer: X = act(An @ Z + b).  16 waves x (32 rows each) x BN cols.
template<int BN, int OUTW, bool L1, bool ACT, bool WBF, bool XF>
__device__ __forceinline__ void gcn_layer(
    int bc, const float* __restrict__ adj, const float* __restrict__ dls,
    const unsigned short* __restrict__ ansh, const unsigned short* __restrict__ ansl,
    unsigned short* __restrict__ andh, unsigned short* __restrict__ andl,
    const unsigned short* __restrict__ zgh, const unsigned short* __restrict__ zgl,
    const float* __restrict__ bias,
    unsigned short* __restrict__ xoh, unsigned short* __restrict__ xol,
    float* __restrict__ xf,
    unsigned short* aP0, unsigned short* aP1,
    unsigned short* zP0, unsigned short* zP1)
{
    constexpr int C = BN / 16;
    const int t = threadIdx.x, w = t >> 6, lane = t & 63;
    const int m0 = lane & 15, quad = lane >> 4;

    v4f acc[2][C];
    #pragma unroll
    for (int r = 0; r < 2; ++r)
        #pragma unroll
        for (int c = 0; c < C; ++c) acc[r][c] = (v4f){0.f, 0.f, 0.f, 0.f};

    for (int kb = 0; kb < 16; ++kb) {
        __syncthreads();                        // previous panel consumers done
        if constexpr (L1) {
            // fused convert: An = D(adj+I)D, bit-identical to old k_convert
            const int ci = t >> 2, cj = (t & 3) * 8;
            #pragma unroll
            for (int pass = 0; pass < 2; ++pass) {
                const int i = pass * 256 + ci;
                const int gj = kb * 32 + cj;
                const float* ap = adj + (size_t)bc * NN * NN + (size_t)i * NN + gj;
                float4 a0 = *(const float4*)ap;
                float4 a1 = *(const float4*)(ap + 4);
                const float di = dls[i];
                const float4 d0 = *(const float4*)(dls + gj);
                const float4 d1 = *(const float4*)(dls + gj + 4);
                float av[8] = { a0.x,a0.y,a0.z,a0.w,a1.x,a1.y,a1.z,a1.w };
                float dv[8] = { d0.x,d0.y,d0.z,d0.w,d1.x,d1.y,d1.z,d1.w };
                unsigned pw[4], qw[4];
                #pragma unroll
                for (int q = 0; q < 4; ++q) {
                    unsigned short h0, l0, h1, l1;
                    float u0 = di * dv[2*q]   * (av[2*q]   + ((gj+2*q)   == i ? 1.f : 0.f));
                    float u1 = di * dv[2*q+1] * (av[2*q+1] + ((gj+2*q+1) == i ? 1.f : 0.f));
                    bsplit(u0, h0, l0); bsplit(u1, h1, l1);
                    pw[q] = (unsigned)h0 | ((unsigned)h1 << 16);
                    qw[q] = (unsigned)l0 | ((unsigned)l1 << 16);
                }
                const int lofs = (i >> 4) * 512 + ((i & 15) + 16 * (cj >> 3)) * 8;
                const size_t go = ((size_t)(i >> 4) * 16 + kb) * 512
                                + (size_t)(((i & 15) + 16 * (cj >> 3)) * 8);
                uint4 ph; ph.x = pw[0]; ph.y = pw[1]; ph.z = pw[2]; ph.w = pw[3];
                uint4 pl; pl.x = qw[0]; pl.y = qw[1]; pl.z = qw[2]; pl.w = qw[3];
                *(uint4*)(aP0 + lofs) = ph;
                *(uint4*)(aP1 + lofs) = pl;
                *(uint4*)(andh + go) = ph;      // persist for layers 2-4
                *(uint4*)(andl + go) = pl;
            }
        } else {
            // stage An panel from frag-order global (2048 16B chunks/plane)
            #pragma unroll
            for (int q = 0; q < 2; ++q) {
                const int c0 = q * 1024 + (t & ~63);
                const int c  = c0 + lane;
                const size_t go = ((size_t)(c >> 6) * 16 + kb) * 512 + (size_t)((c & 63) * 8);
                gl_lds16(ansh + go, aP0 + (size_t)c0 * 8);
                gl_lds16(ansl + go, aP1 + (size_t)c0 * 8);
            }
        }
        if (t < BN * 4) {                       // Z panel (BN*4 chunks/plane)
            const int c0 = t & ~63, c = t;
            const size_t go = ((size_t)(c >> 6) * 16 + kb) * 512 + (size_t)((c & 63) * 8);
            gl_lds16(zgh + go, zP0 + (size_t)c0 * 8);
            gl_lds16(zgl + go, zP1 + (size_t)c0 * 8);
        }
        __syncthreads();                        // panel visible (drains vm+lgkm)

        const int r0 = w * 2;
        v8bf ah0 = *(const v8bf*)(aP0 + (size_t)(r0    ) * 512 + lane * 8);
        v8bf al0 = *(const v8bf*)(aP1 + (size_t)(r0    ) * 512 + lane * 8);
        v8bf ah1 = *(const v8bf*)(aP0 + (size_t)(r0 + 1) * 512 + lane * 8);
        v8bf al1 = *(const v8bf*)(aP1 + (size_t)(r0 + 1) * 512 + lane * 8);
        #pragma unroll
        for (int c = 0; c < C; ++c) {
            v8bf zfh = *(const v8bf*)(zP0 + (size_t)c * 512 + lane * 8);
            v8bf zfl = *(const v8bf*)(zP1 + (size_t)c * 512 + lane * 8);
            acc[0][c] = __builtin_amdgcn_mfma_f32_16x16x32_bf16(ah0, zfh, acc[0][c], 0, 0, 0);
            acc[0][c] = __builtin_amdgcn_mfma_f32_16x16x32_bf16(ah0, zfl, acc[0][c], 0, 0, 0);
            acc[0][c] = __builtin_amdgcn_mfma_f32_16x16x32_bf16(al0, zfh, acc[0][c], 0, 0, 0);
            acc[1][c] = __builtin_amdgcn_mfma_f32_16x16x32_bf16(ah1, zfh, acc[1][c], 0, 0, 0);
            acc[1][c] = __builtin_amdgcn_mfma_f32_16x16x32_bf16(ah1, zfl, acc[1][c], 0, 0, 0);
            acc[1][c] = __builtin_amdgcn_mfma_f32_16x16x32_bf16(al1, zfh, acc[1][c], 0, 0, 0);
        }
    }

    // epilogue
    #pragma unroll
    for (int c = 0; c < C; ++c) {
        int col = c * 16 + m0;
        if (OUTW < BN && col >= OUTW) continue;
        float bv = bias[col];
        #pragma unroll
        for (int r = 0; r < 2; ++r) {
            #pragma unroll
            for (int reg = 0; reg < 4; ++reg) {
                int row = w * 32 + r * 16 + quad * 4 + reg;
                float v = acc[r][c][reg] + bv;
                if (ACT) v = v >= 0.f ? v : 0.2f * v;
                if constexpr (XF) xf[(size_t)row * OUTW + col] = v;
                if constexpr (WBF) {
                    unsigned short hh, ll; bsplit(v, hh, ll);
                    size_t o = fa<BN>(row, col);
                    xoh[o] = hh; xol[o] = ll;
                }
            }
        }
    }
}

// ---- Z-gemm: Z[h][j] = sum_p W[p][h] X[j][p]; out frag kext=512 ------------
template<int HOP, int HI>
__device__ __forceinline__ void gcn_zgemm(
    const unsigned short* __restrict__ wth, const unsigned short* __restrict__ wtl,
    const unsigned short* __restrict__ xgh, const unsigned short* __restrict__ xgl,
    unsigned short* __restrict__ zoh, unsigned short* __restrict__ zol,
    unsigned short* aP0, unsigned short* aP1)
{
    constexpr int HT = HOP / 16, JG = 16 / HT, JT = 32 / JG, KS = HI / 32;
    const int t = threadIdx.x, w = t >> 6, lane = t & 63;
    const int m0 = lane & 15, quad = lane >> 4;
    const int hf = w % HT, jg = w / HT;
    v4f acc[JT];
    #pragma unroll
    for (int c = 0; c < JT; ++c) acc[c] = (v4f){0.f, 0.f, 0.f, 0.f};

    for (int ks = 0; ks < KS; ++ks) {
        __syncthreads();
        #pragma unroll
        for (int q = 0; q < 2; ++q) {           // X panel: 2048 chunks/plane
            const int c0 = q * 1024 + (t & ~63);
            const int c  = c0 + lane;
            const size_t go = ((size_t)(c >> 6) * KS + ks) * 512 + (size_t)((c & 63) * 8);
            gl_lds16(xgh + go, aP0 + (size_t)c0 * 8);
            gl_lds16(xgl + go, aP1 + (size_t)c0 * 8);
        }
        __syncthreads();
        const size_t wo = ((size_t)hf * KS + ks) * 512 + (size_t)(lane * 8);
        v8bf wh = *(const v8bf*)(wth + wo);
        v8bf wl = *(const v8bf*)(wtl + wo);
        #pragma unroll
        for (int c = 0; c < JT; ++c) {
            const int jt = jg * JT + c;
            v8bf bxh = *(const v8bf*)(aP0 + (size_t)jt * 512 + lane * 8);
            v8bf bxl = *(const v8bf*)(aP1 + (size_t)jt * 512 + lane * 8);
            acc[c] = __builtin_amdgcn_mfma_f32_16x16x32_bf16(wh, bxh, acc[c], 0, 0, 0);
            acc[c] = __builtin_amdgcn_mfma_f32_16x16x32_bf16(wh, bxl, acc[c], 0, 0, 0);
            acc[c] = __builtin_amdgcn_mfma_f32_16x16x32_bf16(wl, bxh, acc[c], 0, 0, 0);
        }
    }
    #pragma unroll
    for (int c = 0; c < JT; ++c) {
        int j = (jg * JT + c) * 16 + m0;
        #pragma unroll
        for (int reg = 0; reg < 4; ++reg) {
            int h = hf * 16 + quad * 4 + reg;
            unsigned short hh, ll; bsplit(acc[c][reg], hh, ll);
            size_t o = fa<512>(h, j);
            zoh[o] = hh; zol[o] = ll;
        }
    }
}

__global__ __launch_bounds__(1024) void k_gcn(
    const float* __restrict__ adj,
    const unsigned short* __restrict__ zt1h, const unsigned short* __restrict__ zt1l,
    const unsigned short* __restrict__ wt2h, const unsigned short* __restrict__ wt2l,
    const unsigned short* __restrict__ wt3h, const unsigned short* __restrict__ wt3l,
    const unsigned short* __restrict__ wt4h, const unsigned short* __restrict__ wt4l,
    const float* __restrict__ b1p, const float* __restrict__ b1n,
    const float* __restrict__ b2p, const float* __restrict__ b2n,
    const float* __restrict__ b3p, const float* __restrict__ b3n,
    const float* __restrict__ b4p, const float* __restrict__ b4n,
    unsigned short* __restrict__ anh, unsigned short* __restrict__ anl,
    unsigned short* __restrict__ xh, unsigned short* __restrict__ xl,
    unsigned short* __restrict__ zh, unsigned short* __restrict__ zl,
    float* __restrict__ x3f, float* __restrict__ x4f)
{
    __shared__ __align__(16) unsigned short aP0[16384];
    __shared__ __align__(16) unsigned short aP1[16384];
    __shared__ __align__(16) unsigned short zP0[4096];
    __shared__ __align__(16) unsigned short zP1[4096];
    __shared__ float dls[512];

    const int bc = blockIdx.x, s = bc & 1;
    const int t = threadIdx.x, w = t >> 6, lane = t & 63;

    // phase 0: row sums -> dinv in LDS (adj HBM read warms caches)
    {
        const float* A0 = adj + (size_t)bc * NN * NN;
        for (int rr = 0; rr < 32; ++rr) {
            int row = w * 32 + rr;
            const float4* rp = (const float4*)(A0 + (size_t)row * NN);
            float4 v0 = rp[lane], v1 = rp[lane + 64];
            float sm = v0.x + v0.y + v0.z + v0.w + v1.x + v1.y + v1.z + v1.w;
            #pragma unroll
            for (int off = 32; off; off >>= 1) sm += __shfl_down(sm, off, 64);
            if (lane == 0) dls[row] = sm;
        }
        __syncthreads();
        if (t < 512) dls[t] = rsqrtf(1.0f + dls[t]);
        // layer loop starts with __syncthreads()
    }

    unsigned short* anb_h = anh + (size_t)bc * 262144;
    unsigned short* anb_l = anl + (size_t)bc * 262144;
    unsigned short* xb_h  = xh + (size_t)bc * 65536;
    unsigned short* xb_l  = xl + (size_t)bc * 65536;
    unsigned short* zb_h  = zh + (size_t)bc * 32768;
    unsigned short* zb_l  = zl + (size_t)bc * 32768;

    gcn_layer<128, 128, true, true, true, false>(bc, adj, dls,
        nullptr, nullptr, anb_h, anb_l,
        zt1h + s * 65536, zt1l + s * 65536, s ? b1n : b1p,
        xb_h, xb_l, nullptr, aP0, aP1, zP0, zP1);
    gcn_zgemm<64, 128>(wt2h + s * 8192, wt2l + s * 8192, xb_h, xb_l, zb_h, zb_l, aP0, aP1);
    gcn_layer<64, 64, false, true, true, false>(bc, adj, dls,
        anb_h, anb_l, nullptr, nullptr,
        zb_h, zb_l, s ? b2n : b2p, xb_h, xb_l, nullptr, aP0, aP1, zP0, zP1);
    gcn_zgemm<32, 64>(wt3h + s * 2048, wt3l + s * 2048, xb_h, xb_l, zb_h, zb_l, aP0, aP1);
    gcn_layer<32, 32, false, true, true, true>(bc, adj, dls,
        anb_h, anb_l, nullptr, nullptr,
        zb_h, zb_l, s ? b3n : b3p, xb_h, xb_l, x3f + (size_t)bc * 16384, aP0, aP1, zP0, zP1);
    gcn_zgemm<16, 32>(wt4h + s * 512, wt4l + s * 512, xb_h, xb_l, zb_h, zb_l, aP0, aP1);
    gcn_layer<16, 8, false, false, false, true>(bc, adj, dls,
        anb_h, anb_l, nullptr, nullptr,
        zb_h, zb_l, s ? b4n : b4p, nullptr, nullptr, x4f + (size_t)bc * 4096, aP0, aP1, zP0, zP1);
}

// ================= FALLBACK (R2 proven path, fp32 vector) ===================
template<int H, int HP, bool SHARED, bool ACT>
__global__ __launch_bounds__(256) void k_biggemm(
    const float* __restrict__ adj, const float* __restrict__ zcg,
    const float* __restrict__ wp, const float* __restrict__ wn,
    const float* __restrict__ bp, const float* __restrict__ bn,
    const float* __restrict__ dinv, float* __restrict__ xout)
{
    constexpr int CPT = HP / 16;
    constexpr int KT = 64;
    __shared__ float a_s[64 * 68];
    __shared__ float z_s[KT * H];
    const int bc = blockIdx.y;
    const int rt = blockIdx.x;
    const int t  = threadIdx.x;
    const int tx = t & 15, ty = t >> 4;
    const float* A    = adj + (size_t)bc * NN * NN + (size_t)rt * 64 * NN;
    const float* dloc = dinv + bc * NN;
    const float* ZG   = SHARED ? ((bc & 1) ? wn : wp) : (zcg + (size_t)bc * NN * H);
    const float* bias = (bc & 1) ? bn : bp;
    float acc[4][CPT];
    #pragma unroll
    for (int r = 0; r < 4; ++r)
        #pragma unroll
        for (int u = 0; u < CPT; ++u) acc[r][u] = 0.f;
    for (int kb = 0; kb < NN; kb += KT) {
        __syncthreads();
        #pragma unroll
        for (int l = 0; l < 4; ++l) {
            int idx = t + l * 256;
            int r = idx >> 4, q = idx & 15;
            float4 v = *(const float4*)(A + (size_t)r * NN + kb + q * 4);
            *(float4*)(a_s + r * 68 + q * 4) = v;
        }
        constexpr int NZ4 = KT * H / 4;
        for (int idx = t; idx < NZ4; idx += 256) {
            int k = idx / (H / 4), hq = idx % (H / 4);
            float4 v = *(const float4*)(ZG + (size_t)(kb + k) * H + hq * 4);
            if (SHARED) {
                float dk = dloc[kb + k];
                v.x *= dk; v.y *= dk; v.z *= dk; v.w *= dk;
            }
            *(float4*)(z_s + k * H + hq * 4) = v;
        }
        __syncthreads();
        #pragma unroll 8
        for (int k = 0; k < KT; ++k) {
            float ar[4];
            #pragma unroll
            for (int r = 0; r < 4; ++r) ar[r] = a_s[(ty * 4 + r) * 68 + k];
            float zv[CPT];
            #pragma unroll
            for (int u = 0; u < CPT; ++u) {
                int h = tx * CPT + u;
                if (H < HP && h >= H) h = 0;
                zv[u] = z_s[k * H + h];
            }
            #pragma unroll
            for (int r = 0; r < 4; ++r)
                #pragma unroll
                for (int u = 0; u < CPT; ++u)
                    acc[r][u] += ar[r] * zv[u];
        }
    }
    #pragma unroll
    for (int r = 0; r < 4; ++r) {
        int i = rt * 64 + ty * 4 + r;
        float di = dloc[i];
        #pragma unroll
        for (int u = 0; u < CPT; ++u) {
            int h = tx * CPT + u;
            if (H < HP && h >= H) continue;
            float self = SHARED ? di * ZG[(size_t)i * H + h] : ZG[(size_t)i * H + h];
            float v = di * (acc[r][u] + self) + bias[h];
            if (ACT) v = v >= 0.f ? v : 0.2f * v;
            xout[((size_t)bc * NN + i) * H + h] = v;
        }
    }
}

template<int HI, int HO>
__global__ __launch_bounds__(256) void k_smallgemm(
    const float* __restrict__ xin, const float* __restrict__ wp,
    const float* __restrict__ wn, const float* __restrict__ dinv,
    float* __restrict__ zc)
{
    constexpr int CPT = (HO >= 16) ? HO / 16 : 1;
    constexpr int XS = HI + 4;
    __shared__ float x_s[32 * XS];
    __shared__ float w_s[HI * HO];
    const int bc = blockIdx.y, jt = blockIdx.x, t = threadIdx.x;
    const int tx = t & 15, ty = t >> 4;
    const float* W = (bc & 1) ? wn : wp;
    const float* X = xin + ((size_t)bc * NN + jt * 32) * HI;
    for (int idx = t; idx < HI * HO / 4; idx += 256)
        *(float4*)(w_s + idx * 4) = *(const float4*)(W + idx * 4);
    for (int idx = t; idx < 32 * HI / 4; idx += 256) {
        int r = idx / (HI / 4), q = idx % (HI / 4);
        *(float4*)(x_s + r * XS + q * 4) = *(const float4*)(X + (size_t)r * HI + q * 4);
    }
    __syncthreads();
    float acc[2][CPT];
    #pragma unroll
    for (int r = 0; r < 2; ++r)
        #pragma unroll
        for (int u = 0; u < CPT; ++u) acc[r][u] = 0.f;
    #pragma unroll 4
    for (int p = 0; p < HI; ++p) {
        float xr[2];
        #pragma unroll
        for (int r = 0; r < 2; ++r) xr[r] = x_s[(ty * 2 + r) * XS + p];
        float wv[CPT];
        #pragma unroll
        for (int u = 0; u < CPT; ++u) {
            int h = tx * CPT + u;
            if (HO < 16 && h >= HO) h = 0;
            wv[u] = w_s[p * HO + h];
        }
        #pragma unroll
        for (int r = 0; r < 2; ++r)
            #pragma unroll
            for (int u = 0; u < CPT; ++u) acc[r][u] += xr[r] * wv[u];
    }
    const float* dloc = dinv + bc * NN;
    #pragma unroll
    for (int r = 0; r < 2; ++r) {
        int j = jt * 32 + ty * 2 + r;
        float dj = dloc[j];
        #pragma unroll
        for (int u = 0; u < CPT; ++u) {
            int h = tx * CPT + u;
            if (HO < 16 && h >= HO) continue;
            zc[((size_t)bc * NN + j) * HO + h] = dj * acc[r][u];
        }
    }
}

// ---------------- DCL head (shared by both paths) ---------------------------
__global__ __launch_bounds__(256) void k_dcl(
    const float* __restrict__ x3, const float* __restrict__ x4,
    const float* __restrict__ wc, const int* __restrict__ task,
    float* __restrict__ L)
{
    __shared__ float ps[8][32];
    __shared__ float xf[32];
    __shared__ float pr[72];
    const int bc = blockIdx.x, t = threadIdx.x;
    const float* X3 = x3 + (size_t)bc * NN * 32;
    {
        int col = t & 31, rg = t >> 5;
        float s = 0.f;
        for (int r = rg; r < NN; r += 8) s += X3[r * 32 + col];
        ps[rg][col] = s;
    }
    __syncthreads();
    if (t < 32) {
        float s = 0.f;
        #pragma unroll
        for (int g = 0; g < 8; ++g) s += ps[g][t];
        xf[t] = s * (1.0f / 512.0f);
    }
    __syncthreads();
    if (t < 72) {
        int tid = task[bc >> 1];
        const float* wr = wc + t * 48;
        float s = wr[32 + tid];
        #pragma unroll
        for (int j = 0; j < 32; ++j) s += wr[j] * xf[j];
        pr[t] = s;
    }
    __syncthreads();
    const float* X4 = x4 + (size_t)bc * 4096;
    float* Lb = L + (size_t)bc * 4096;
    #pragma unroll
    for (int rep = 0; rep < 2; ++rep) {
        int n = rep * 256 + t;
        float hi[8];
        #pragma unroll
        for (int i = 0; i < 8; ++i) hi[i] = X4[i * 512 + n];
        #pragma unroll
        for (int o = 0; o < 8; ++o) {
            float s = pr[64 + o];
            #pragma unroll
            for (int i = 0; i < 8; ++i) s += pr[o * 8 + i] * hi[i];
            Lb[o * 512 + n] = s;
        }
    }
}

// ---------------- final: out[bc][n][m] = softplus(-cc_n . cc_m) -------------
#define SCP 520
__global__ __launch_bounds__(256) void k_final(const float* __restrict__ L,
                                               float* __restrict__ out)
{
    __shared__ float scT[8 * SCP];
    const int bcid = blockIdx.y;
    const int b = bcid >> 1, c = bcid & 1;
    const int nt = blockIdx.x, t = threadIdx.x;
    const float* Lp = L + (size_t)(b * 2) * 4096;
    const float* Ln = Lp + 4096;
    for (int rep = 0; rep < 16; ++rep) {
        int e = rep * 256 + t;
        int f = c * 4096 + e;
        int n = f >> 4, k = f & 15;
        float v = (k < 8) ? Lp[n * 8 + k] : Ln[n * 8 + k - 8];
        scT[(e & 7) * SCP + (e >> 3)] = v;
    }
    __syncthreads();
    const int tx = t & 63, ty = t >> 6;
    const int n0 = nt * 32 + ty * 8;
    float cn[8][8];
    #pragma unroll
    for (int o = 0; o < 8; ++o)
        #pragma unroll
        for (int i = 0; i < 8; ++i) cn[i][o] = scT[o * SCP + n0 + i];
    float* ob = out + (size_t)bcid * NN * NN;
    #pragma unroll 2
    for (int mg = 0; mg < 8; ++mg) {
        int m = tx + mg * 64;
        float cm[8];
        #pragma unroll
        for (int o = 0; o < 8; ++o) cm[o] = scT[o * SCP + m];
        #pragma unroll
        for (int i = 0; i < 8; ++i) {
            float s = 0.f;
            #pragma unroll
            for (int o = 0; o < 8; ++o) s += cn[i][o] * cm[o];
            float r = fmaxf(-s, 0.f) + __logf(1.0f + __expf(-fabsf(s)));
            ob[(size_t)(n0 + i) * NN + m] = r;
        }
    }
}

extern "C" void kernel_launch(void* const* d_in, const int* in_sizes, int n_in,
                              void* d_out, int out_size, void* d_ws, size_t ws_size,
                              hipStream_t stream)
{
    const float* adj = (const float*)d_in[0];
    const int*  task = (const int*)d_in[1];
    const float* w1p = (const float*)d_in[2];  const float* b1p = (const float*)d_in[3];
    const float* w2p = (const float*)d_in[4];  const float* b2p = (const float*)d_in[5];
    const float* w3p = (const float*)d_in[6];  const float* b3p = (const float*)d_in[7];
    const float* w4p = (const float*)d_in[8];  const float* b4p = (const float*)d_in[9];
    const float* w1n = (const float*)d_in[10]; const float* b1n = (const float*)d_in[11];
    const float* w2n = (const float*)d_in[12]; const float* b2n = (const float*)d_in[13];
    const float* w3n = (const float*)d_in[14]; const float* b3n = (const float*)d_in[15];
    const float* w4n = (const float*)d_in[16]; const float* b4n = (const float*)d_in[17];
    const float* wc  = (const float*)d_in[18];
    (void)in_sizes; (void)n_in; (void)out_size;

    const size_t NEED = 197742592ull;
    if (ws_size >= NEED) {
        char* base = (char*)d_ws;
        unsigned short* anh  = (unsigned short*)(base + 0);
        unsigned short* anl  = (unsigned short*)(base + 67108864);
        unsigned short* xh   = (unsigned short*)(base + 134217728);
        unsigned short* xl   = (unsigned short*)(base + 150994944);
        unsigned short* zh   = (unsigned short*)(base + 167772160);
        unsigned short* zl   = (unsigned short*)(base + 176160768);
        unsigned short* zt1h = (unsigned short*)(base + 184549376);
        unsigned short* zt1l = (unsigned short*)(base + 184811520);
        unsigned short* wt2h = (unsigned short*)(base + 185073664);
        unsigned short* wt2l = (unsigned short*)(base + 185106432);
        unsigned short* wt3h = (unsigned short*)(base + 185139200);
        unsigned short* wt3l = (unsigned short*)(base + 185147392);
        unsigned short* wt4h = (unsigned short*)(base + 185155584);
        unsigned short* wt4l = (unsigned short*)(base + 185157632);
        float*          x3f  = (float*)(base + 185159680);
        float*          x4f  = (float*)(base + 193548288);
        float*          L    = (float*)(base + 195645440);

        WJobs jobs;
        jobs.j[0] = {w1p, zt1h,          zt1l,          512, 128, 128};
        jobs.j[1] = {w1n, zt1h + 65536,  zt1l + 65536,  512, 128, 128};
        jobs.j[2] = {w2p, wt2h,          wt2l,          128,  64,  64};
        jobs.j[3] = {w2n, wt2h + 8192,   wt2l + 8192,   128,  64,  64};
        jobs.j[4] = {w3p, wt3h,          wt3l,           64,  32,  32};
        jobs.j[5] = {w3n, wt3h + 2048,   wt3l + 2048,    64,  32,  32};
        jobs.j[6] = {w4p, wt4h,          wt4l,           32,   8,  16};
        jobs.j[7] = {w4n, wt4h + 512,    wt4l + 512,     32,   8,  16};
        k_wprep<<<dim3(256, 8), 256, 0, stream>>>(jobs);

        k_gcn<<<dim3(NBC), 1024, 0, stream>>>(adj,
            zt1h, zt1l, wt2h, wt2l, wt3h, wt3l, wt4h, wt4l,
            b1p, b1n, b2p, b2n, b3p, b3n, b4p, b4n,
            anh, anl, xh, xl, zh, zl, x3f, x4f);

        k_dcl<<<dim3(NBC), 256, 0, stream>>>(x3f, x4f, wc, task, L);
        k_final<<<dim3(16, NBC), 256, 0, stream>>>(L, (float*)d_out);
    } else {
        // -------- fallback: proven R2 fp32 path (needs ~63 MB) --------
        float* ws   = (float*)d_ws;
        float* dinv = ws;
        float* XA   = ws + 65536;
        float* X3   = XA + 8388608;
        float* X4   = X3 + 2097152;
        float* L    = X4 + 524288;
        float* ZC   = L  + 524288;
        k_rowsum<<<dim3(NBC * NN / 4), 256, 0, stream>>>(adj, dinv);
        k_biggemm<128,128,true ,true ><<<dim3(8,128), 256, 0, stream>>>(adj, nullptr, w1p, w1n, b1p, b1n, dinv, XA);
        k_smallgemm<128,64><<<dim3(16,128), 256, 0, stream>>>(XA, w2p, w2n, dinv, ZC);
        k_biggemm<64,64,false,true ><<<dim3(8,128), 256, 0, stream>>>(adj, ZC, nullptr, nullptr, b2p, b2n, dinv, XA);
        k_smallgemm<64,32><<<dim3(16,128), 256, 0, stream>>>(XA, w3p, w3n, dinv, ZC);
        k_biggemm<32,32,false,true ><<<dim3(8,128), 256, 0, stream>>>(adj, ZC, nullptr, nullptr, b3p, b3n, dinv, X3);
        k_smallgemm<32,8><<<dim3(16,128), 256, 0, stream>>>(X3, w4p, w4n, dinv, ZC);
        k_biggemm<8,16,false,false><<<dim3(8,128), 256, 0, stream>>>(adj, ZC, nullptr, nullptr, b4p, b4n, dinv, X4);
        k_dcl<<<dim3(128), 256, 0, stream>>>(X3, X4, wc, task, L);
        k_final<<<dim3(16,128), 256, 0, stream>>>(L, (float*)d_out);
    }
}